// Round 7
// baseline (247.685 us; speedup 1.0000x reference)
//
#include <hip/hip_runtime.h>
#include <hip/hip_fp16.h>

typedef __attribute__((ext_vector_type(4))) float f32x4;
typedef __attribute__((ext_vector_type(8))) _Float16 h8;
typedef __attribute__((ext_vector_type(4))) _Float16 h4;
typedef __attribute__((ext_vector_type(2))) _Float16 h2;
typedef __attribute__((ext_vector_type(2))) __fp16 fp16x2;

// ---------------------------------------------------------------- helpers
__device__ __forceinline__ void gld16(const _Float16* g, _Float16* l) {
  __builtin_amdgcn_global_load_lds(
      (const __attribute__((address_space(1))) void*)g,
      (__attribute__((address_space(3))) void*)l, 16, 0, 0);
}

__device__ __forceinline__ h4 pack4(float p0, float p1, float p2, float p3) {
  fp16x2 lo = __builtin_amdgcn_cvt_pkrtz(p0, p1);
  fp16x2 hi = __builtin_amdgcn_cvt_pkrtz(p2, p3);
  h2 lo2 = __builtin_bit_cast(h2, lo);
  h2 hi2 = __builtin_bit_cast(h2, hi);
  return __builtin_shufflevector(lo2, hi2, 0, 1, 2, 3);
}

// ---------------------------------------------------------------- convert f32 -> f16 (vectorized)
__global__ void cvt_f32_h(const float* __restrict__ in, _Float16* __restrict__ out, int n8) {
  for (int i = blockIdx.x * blockDim.x + threadIdx.x; i < n8; i += gridDim.x * blockDim.x) {
    const f32x4* p = (const f32x4*)(in + (size_t)i * 8);
    f32x4 a = p[0], b = p[1];
    h8 o;
    o[0] = (_Float16)a[0]; o[1] = (_Float16)a[1]; o[2] = (_Float16)a[2]; o[3] = (_Float16)a[3];
    o[4] = (_Float16)b[0]; o[5] = (_Float16)b[1]; o[6] = (_Float16)b[2]; o[7] = (_Float16)b[3];
    *(h8*)(out + (size_t)i * 8) = o;
  }
}

// ---------------------------------------------------------------- transpose + convert: in[R][C] f32 -> out[C][R] f16
__global__ void transpose_cvt(const float* __restrict__ in, _Float16* __restrict__ out, int R, int C) {
  __shared__ float tile[32][33];
  const int tx = threadIdx.x & 31, ty = threadIdx.x >> 5;
  const int c = blockIdx.x * 32 + tx;
#pragma unroll
  for (int j = 0; j < 32; j += 8) {
    int r = blockIdx.y * 32 + ty + j;
    tile[ty + j][tx] = in[(size_t)r * C + c];
  }
  __syncthreads();
#pragma unroll
  for (int j = 0; j < 32; j += 8) {
    out[(size_t)(blockIdx.x * 32 + ty + j) * R + blockIdx.y * 32 + tx] = (_Float16)tile[tx][ty + j];
  }
}

// ---------------------------------------------------------------- GEMM (m97 structure)
template <int EPI>
__global__ __launch_bounds__(256, 2)
void gemm_kernel(const _Float16* __restrict__ A, const _Float16* __restrict__ Bt,
                 float* __restrict__ outF, const float* __restrict__ bias,
                 _Float16* __restrict__ q_h, _Float16* __restrict__ k_h,
                 _Float16* __restrict__ v_t, const int Nn, const int K) {
  __shared__ _Float16 As[128 * 64];
  __shared__ _Float16 Bs[128 * 64];
  const int tid = threadIdx.x;
  const int wid = tid >> 6, lane = tid & 63;
  const int g = lane >> 4, r16 = lane & 15;
  const int wr = wid >> 1, wc = wid & 1;
  const int row0 = blockIdx.x * 128;
  const int col0 = blockIdx.y * 128;
  f32x4 acc[4][4] = {};
  const int sr = tid >> 3, sc = tid & 7;
  const _Float16* ag = A + (size_t)(row0 + sr) * K + sc * 8;
  const _Float16* bg = Bt + (size_t)(col0 + sr) * K + sc * 8;

  for (int kt = 0; kt < K; kt += 64) {
    __syncthreads();
#pragma unroll
    for (int i = 0; i < 4; ++i)
      gld16(ag + (size_t)i * 32 * K + kt, As + i * 2048 + wid * 512);
#pragma unroll
    for (int i = 0; i < 4; ++i)
      gld16(bg + (size_t)i * 32 * K + kt, Bs + i * 2048 + wid * 512);
    __syncthreads();

#pragma unroll
    for (int kk = 0; kk < 2; ++kk) {
      h8 af[4], bf[4];
#pragma unroll
      for (int mt = 0; mt < 4; ++mt)
        af[mt] = *(const h8*)(As + (wr * 64 + mt * 16 + r16) * 64 + kk * 32 + g * 8);
#pragma unroll
      for (int nt = 0; nt < 4; ++nt)
        bf[nt] = *(const h8*)(Bs + (wc * 64 + nt * 16 + r16) * 64 + kk * 32 + g * 8);
#pragma unroll
      for (int mt = 0; mt < 4; ++mt)
#pragma unroll
        for (int nt = 0; nt < 4; ++nt)
          acc[mt][nt] = __builtin_amdgcn_mfma_f32_16x16x32_f16(af[mt], bf[nt], acc[mt][nt], 0, 0, 0);
    }
  }

  if (EPI == 0) {
    const float qscale = 0.125f * 1.44269504088896340736f;  // 1/sqrt(64) * log2(e)
#pragma unroll
    for (int mt = 0; mt < 4; ++mt) {
#pragma unroll
      for (int nt = 0; nt < 4; ++nt) {
        const int j = col0 + wc * 64 + nt * 16 + r16;
        const int which = j >> 10;
        const int hd = j & 1023;
        const int hh = hd >> 6, dd = hd & 63;
#pragma unroll
        for (int rg = 0; rg < 4; ++rg) {
          const int mm = row0 + wr * 64 + mt * 16 + g * 4 + rg;
          const int b = mm >> 11, n = mm & 2047;
          const size_t bh = (size_t)(b * 16 + hh);
          const float v = acc[mt][nt][rg];
          if (which == 0)      q_h[(bh * 2048 + n) * 64 + dd] = (_Float16)(v * qscale);
          else if (which == 1) k_h[(bh * 2048 + n) * 64 + dd] = (_Float16)v;
          else                 v_t[(bh * 64 + dd) * 2048 + n] = (_Float16)v;
        }
      }
    }
  } else {
#pragma unroll
    for (int mt = 0; mt < 4; ++mt) {
#pragma unroll
      for (int nt = 0; nt < 4; ++nt) {
        const int j = col0 + wc * 64 + nt * 16 + r16;
        const float bv = bias[j];
#pragma unroll
        for (int rg = 0; rg < 4; ++rg) {
          const int mm = row0 + wr * 64 + mt * 16 + g * 4 + rg;
          outF[(size_t)mm * Nn + j] = acc[mt][nt][rg] + bv;
        }
      }
    }
  }
}

// ---------------------------------------------------------------- flash attention (v7)
// 128 q-rows/block (4 waves x 32 q), grid 1024 -> 4 blocks/CU, 16 waves/CU.
// LDS = 32 KB KV dbuf; Q direct->reg; epilogue reuses KV smem. No launch-bound clamp.
__device__ __forceinline__ void stage_kv(const _Float16* Kg, const _Float16* Vg,
                                         _Float16* KsB, _Float16* VsB,
                                         int kv0, int sr, int sc8, int wid) {
#pragma unroll
  for (int i = 0; i < 2; ++i) {
    int r = i * 32 + sr;
    gld16(Kg + (size_t)(kv0 + r) * 64 + (sc8 ^ ((r & 7) * 8)), KsB + i * 2048 + wid * 512);
    gld16(Vg + (size_t)r * 2048 + kv0 + (sc8 ^ ((r & 7) * 8)), VsB + i * 2048 + wid * 512);
  }
}

__global__ __launch_bounds__(256, 2)
void attn_kernel(const _Float16* __restrict__ Qall, const _Float16* __restrict__ Kall,
                 const _Float16* __restrict__ Vtall, _Float16* __restrict__ Oall) {
  __shared__ _Float16 smem[2][2][64 * 64];   // [buf][K/V] = 32 KB total
  const int tid = threadIdx.x;
  const int wid = tid >> 6, lane = tid & 63;
  const int g = lane >> 4, r16 = lane & 15;
  // bijective XCD remap (nwg=1024, 128/XCD): 16 q-tiles of one (b,h) on one XCD
  const int blk = (blockIdx.x & 7) * 128 + (blockIdx.x >> 3);
  const int qt = blk & 15;
  const int bh = blk >> 4;
  const _Float16* Qg = Qall + (size_t)bh * (2048 * 64);
  const _Float16* Kg = Kall + (size_t)bh * (2048 * 64);
  const _Float16* Vg = Vtall + (size_t)bh * (2048 * 64);
  const int q0 = qt * 128;
  const int sr = tid >> 3, sc8 = (tid & 7) * 8;

  // Q fragments: 2 q-blocks x (d 0..31, 32..63), direct global->reg (one-time)
  h8 qf[2][2];
#pragma unroll
  for (int qb = 0; qb < 2; ++qb) {
    const int qrow = q0 + wid * 32 + qb * 16 + r16;
#pragma unroll
    for (int kd = 0; kd < 2; ++kd)
      qf[qb][kd] = *(const h8*)(Qg + (size_t)qrow * 64 + kd * 32 + g * 8);
  }
  stage_kv(Kg, Vg, smem[0][0], smem[0][1], 0, sr, sc8, wid);
  __syncthreads();

  f32x4 ot[2][4] = {};
  float m[2] = {-3.0e38f, -3.0e38f}, l[2] = {0.f, 0.f};

  auto compute = [&](const _Float16* KsB, const _Float16* VsB) {
    h8 kf[4][2];
#pragma unroll
    for (int kb = 0; kb < 4; ++kb) {
      const int krow = kb * 16 + r16;
#pragma unroll
      for (int kd = 0; kd < 2; ++kd)
        kf[kb][kd] = *(const h8*)(KsB + krow * 64 + ((kd * 32 + g * 8) ^ ((krow & 7) * 8)));
    }
    h4 vf[4][4];
#pragma unroll
    for (int db = 0; db < 4; ++db) {
      const int vrow = db * 16 + r16;
#pragma unroll
      for (int kg = 0; kg < 4; ++kg)
        vf[db][kg] = *(const h4*)(VsB + vrow * 64 + ((kg * 16 + g * 4) ^ ((vrow & 7) * 8)));
    }
#pragma unroll
    for (int qb = 0; qb < 2; ++qb) {
      // S^T: kd outer / kb inner -> dep distance 4
      f32x4 st[4];
      __builtin_amdgcn_s_setprio(1);
#pragma unroll
      for (int kb = 0; kb < 4; ++kb) {
        f32x4 z = {};
        st[kb] = __builtin_amdgcn_mfma_f32_16x16x32_f16(kf[kb][0], qf[qb][0], z, 0, 0, 0);
      }
#pragma unroll
      for (int kb = 0; kb < 4; ++kb)
        st[kb] = __builtin_amdgcn_mfma_f32_16x16x32_f16(kf[kb][1], qf[qb][1], st[kb], 0, 0, 0);
      __builtin_amdgcn_s_setprio(0);

      // max-reduce tree (fuses to v_max3)
      float a0 = fmaxf(fmaxf(st[0][0], st[0][1]), fmaxf(st[0][2], st[0][3]));
      float a1 = fmaxf(fmaxf(st[1][0], st[1][1]), fmaxf(st[1][2], st[1][3]));
      float a2 = fmaxf(fmaxf(st[2][0], st[2][1]), fmaxf(st[2][2], st[2][3]));
      float a3 = fmaxf(fmaxf(st[3][0], st[3][1]), fmaxf(st[3][2], st[3][3]));
      float pmax = fmaxf(fmaxf(a0, a1), fmaxf(a2, a3));
      pmax = fmaxf(pmax, __shfl_xor(pmax, 16));
      pmax = fmaxf(pmax, __shfl_xor(pmax, 32));
      if (__any(pmax > m[qb] + 8.f)) {   // defer-max
        const float mn = fmaxf(m[qb], pmax);
        const float corr = __builtin_amdgcn_exp2f(m[qb] - mn);
        l[qb] *= corr;
#pragma unroll
        for (int db = 0; db < 4; ++db) ot[qb][db] *= corr;
        m[qb] = mn;
      }
      // P = exp2(S - m), VALU row-sum, pack via cvt_pkrtz
      float rs = 0.f;
      h4 pb[4];
#pragma unroll
      for (int kb = 0; kb < 4; ++kb) {
        float p0 = __builtin_amdgcn_exp2f(st[kb][0] - m[qb]);
        float p1 = __builtin_amdgcn_exp2f(st[kb][1] - m[qb]);
        float p2 = __builtin_amdgcn_exp2f(st[kb][2] - m[qb]);
        float p3 = __builtin_amdgcn_exp2f(st[kb][3] - m[qb]);
        rs += (p0 + p1) + (p2 + p3);
        pb[kb] = pack4(p0, p1, p2, p3);
      }
      rs += __shfl_xor(rs, 16);
      rs += __shfl_xor(rs, 32);
      l[qb] += rs;
      // PV: kg outer / db inner -> dep distance 4
      __builtin_amdgcn_s_setprio(1);
#pragma unroll
      for (int kg = 0; kg < 4; ++kg)
#pragma unroll
        for (int db = 0; db < 4; ++db)
          ot[qb][db] = __builtin_amdgcn_mfma_f32_16x16x16f16(vf[db][kg], pb[kg], ot[qb][db], 0, 0, 0);
      __builtin_amdgcn_s_setprio(0);
    }
  };

#pragma unroll 1
  for (int tt = 0; tt < 16; ++tt) {
    stage_kv(Kg, Vg, smem[1][0], smem[1][1], (tt * 2 + 1) * 64, sr, sc8, wid);
    compute(smem[0][0], smem[0][1]);
    __syncthreads();
    if (tt < 15) stage_kv(Kg, Vg, smem[0][0], smem[0][1], (tt * 2 + 2) * 64, sr, sc8, wid);
    compute(smem[1][0], smem[1][1]);
    __syncthreads();
  }

  // epilogue: O^T -> smem (16 KB of 32, swizzled) -> coalesced 16B stores
  _Float16* olds = &smem[0][0][0];
#pragma unroll
  for (int qb = 0; qb < 2; ++qb) {
    const float inv = 1.f / l[qb];
    const int qrow = wid * 32 + qb * 16 + r16;
    const int x = (qrow & 7) * 8;
#pragma unroll
    for (int db = 0; db < 4; ++db) {
      h4 o;
#pragma unroll
      for (int rg = 0; rg < 4; ++rg) o[rg] = (_Float16)(ot[qb][db][rg] * inv);
      *(h4*)(olds + qrow * 64 + ((db * 16 + g * 4) ^ x)) = o;
    }
  }
  __syncthreads();
  const int bb = bh >> 4, hh = bh & 15;
#pragma unroll
  for (int i = 0; i < 4; ++i) {
    const int idx = tid + i * 256;
    const int q = idx >> 3, c = idx & 7;
    h8 vv = *(const h8*)(olds + q * 64 + ((c * 8) ^ ((q & 7) * 8)));
    *(h8*)(Oall + ((size_t)(bb * 2048 + q0 + q) * 1024 + hh * 64 + c * 8)) = vv;
  }
}

// ---------------------------------------------------------------- launch
extern "C" void kernel_launch(void* const* d_in, const int* in_sizes, int n_in,
                              void* d_out, int out_size, void* d_ws, size_t ws_size,
                              hipStream_t stream) {
  const float* x     = (const float*)d_in[0];
  const float* w_qkv = (const float*)d_in[1];
  const float* w_out = (const float*)d_in[2];
  const float* b_out = (const float*)d_in[3];
  float* out = (float*)d_out;

  char* ws = (char*)d_ws;
  _Float16* x_h    = (_Float16*)(ws);                    // 16 MB
  _Float16* wqkv_t = (_Float16*)(ws + 16777216);         // 6 MB
  _Float16* wout_t = (_Float16*)(ws + 23068672);         // 2 MB
  _Float16* q_h    = (_Float16*)(ws + 25165824);         // 16 MB [b,h,n,d] (pre-scaled)
  _Float16* k_h    = (_Float16*)(ws + 41943040);         // 16 MB [b,h,n,d]
  _Float16* v_t    = (_Float16*)(ws + 58720256);         // 16 MB [b,h,d,n]
  _Float16* o_h    = (_Float16*)(ws + 75497472);         // 16 MB [b,n,h*d]

  hipLaunchKernelGGL(cvt_f32_h, dim3(2048), dim3(256), 0, stream, x, x_h, (8192 * 1024) / 8);
  hipLaunchKernelGGL(transpose_cvt, dim3(96, 32), dim3(256), 0, stream, w_qkv, wqkv_t, 1024, 3072);
  hipLaunchKernelGGL(transpose_cvt, dim3(32, 32), dim3(256), 0, stream, w_out, wout_t, 1024, 1024);

  hipLaunchKernelGGL((gemm_kernel<0>), dim3(64, 24), dim3(256), 0, stream,
                     x_h, wqkv_t, nullptr, nullptr, q_h, k_h, v_t, 3072, 1024);

  hipLaunchKernelGGL(attn_kernel, dim3(1024), dim3(256), 0, stream, q_h, k_h, v_t, o_h);

  hipLaunchKernelGGL((gemm_kernel<1>), dim3(64, 8), dim3(256), 0, stream,
                     o_h, wout_t, out, b_out, nullptr, nullptr, nullptr, 1024, 1024);
}

// Round 8
// 229.016 us; speedup vs baseline: 1.0815x; 1.0815x over previous
//
#include <hip/hip_runtime.h>
#include <hip/hip_fp16.h>

typedef __attribute__((ext_vector_type(4))) float f32x4;
typedef __attribute__((ext_vector_type(8))) _Float16 h8;
typedef __attribute__((ext_vector_type(4))) _Float16 h4;
typedef __attribute__((ext_vector_type(2))) _Float16 h2;
typedef __attribute__((ext_vector_type(2))) __fp16 fp16x2;

// ---------------------------------------------------------------- helpers
__device__ __forceinline__ void gld16(const _Float16* g, _Float16* l) {
  __builtin_amdgcn_global_load_lds(
      (const __attribute__((address_space(1))) void*)g,
      (__attribute__((address_space(3))) void*)l, 16, 0, 0);
}

__device__ __forceinline__ h4 pack4(float p0, float p1, float p2, float p3) {
  fp16x2 lo = __builtin_amdgcn_cvt_pkrtz(p0, p1);
  fp16x2 hi = __builtin_amdgcn_cvt_pkrtz(p2, p3);
  h2 lo2 = __builtin_bit_cast(h2, lo);
  h2 hi2 = __builtin_bit_cast(h2, hi);
  return __builtin_shufflevector(lo2, hi2, 0, 1, 2, 3);
}

// ---------------------------------------------------------------- convert f32 -> f16 (vectorized)
__global__ void cvt_f32_h(const float* __restrict__ in, _Float16* __restrict__ out, int n8) {
  for (int i = blockIdx.x * blockDim.x + threadIdx.x; i < n8; i += gridDim.x * blockDim.x) {
    const f32x4* p = (const f32x4*)(in + (size_t)i * 8);
    f32x4 a = p[0], b = p[1];
    h8 o;
    o[0] = (_Float16)a[0]; o[1] = (_Float16)a[1]; o[2] = (_Float16)a[2]; o[3] = (_Float16)a[3];
    o[4] = (_Float16)b[0]; o[5] = (_Float16)b[1]; o[6] = (_Float16)b[2]; o[7] = (_Float16)b[3];
    *(h8*)(out + (size_t)i * 8) = o;
  }
}

// ---------------------------------------------------------------- transpose + convert: in[R][C] f32 -> out[C][R] f16
__global__ void transpose_cvt(const float* __restrict__ in, _Float16* __restrict__ out, int R, int C) {
  __shared__ float tile[32][33];
  const int tx = threadIdx.x & 31, ty = threadIdx.x >> 5;
  const int c = blockIdx.x * 32 + tx;
#pragma unroll
  for (int j = 0; j < 32; j += 8) {
    int r = blockIdx.y * 32 + ty + j;
    tile[ty + j][tx] = in[(size_t)r * C + c];
  }
  __syncthreads();
#pragma unroll
  for (int j = 0; j < 32; j += 8) {
    out[(size_t)(blockIdx.x * 32 + ty + j) * R + blockIdx.y * 32 + tx] = (_Float16)tile[tx][ty + j];
  }
}

// ---------------------------------------------------------------- GEMM (m97 structure)
template <int EPI>
__global__ __launch_bounds__(256, 2)
void gemm_kernel(const _Float16* __restrict__ A, const _Float16* __restrict__ Bt,
                 float* __restrict__ outF, const float* __restrict__ bias,
                 _Float16* __restrict__ q_h, _Float16* __restrict__ k_h,
                 _Float16* __restrict__ v_t, const int Nn, const int K) {
  __shared__ _Float16 As[128 * 64];
  __shared__ _Float16 Bs[128 * 64];
  const int tid = threadIdx.x;
  const int wid = tid >> 6, lane = tid & 63;
  const int g = lane >> 4, r16 = lane & 15;
  const int wr = wid >> 1, wc = wid & 1;
  const int row0 = blockIdx.x * 128;
  const int col0 = blockIdx.y * 128;
  f32x4 acc[4][4] = {};
  const int sr = tid >> 3, sc = tid & 7;
  const _Float16* ag = A + (size_t)(row0 + sr) * K + sc * 8;
  const _Float16* bg = Bt + (size_t)(col0 + sr) * K + sc * 8;

  for (int kt = 0; kt < K; kt += 64) {
    __syncthreads();
#pragma unroll
    for (int i = 0; i < 4; ++i)
      gld16(ag + (size_t)i * 32 * K + kt, As + i * 2048 + wid * 512);
#pragma unroll
    for (int i = 0; i < 4; ++i)
      gld16(bg + (size_t)i * 32 * K + kt, Bs + i * 2048 + wid * 512);
    __syncthreads();

#pragma unroll
    for (int kk = 0; kk < 2; ++kk) {
      h8 af[4], bf[4];
#pragma unroll
      for (int mt = 0; mt < 4; ++mt)
        af[mt] = *(const h8*)(As + (wr * 64 + mt * 16 + r16) * 64 + kk * 32 + g * 8);
#pragma unroll
      for (int nt = 0; nt < 4; ++nt)
        bf[nt] = *(const h8*)(Bs + (wc * 64 + nt * 16 + r16) * 64 + kk * 32 + g * 8);
#pragma unroll
      for (int mt = 0; mt < 4; ++mt)
#pragma unroll
        for (int nt = 0; nt < 4; ++nt)
          acc[mt][nt] = __builtin_amdgcn_mfma_f32_16x16x32_f16(af[mt], bf[nt], acc[mt][nt], 0, 0, 0);
    }
  }

  if (EPI == 0) {
    const float qscale = 0.125f * 1.44269504088896340736f;  // 1/sqrt(64) * log2(e)
#pragma unroll
    for (int mt = 0; mt < 4; ++mt) {
#pragma unroll
      for (int nt = 0; nt < 4; ++nt) {
        const int j = col0 + wc * 64 + nt * 16 + r16;
        const int which = j >> 10;
        const int hd = j & 1023;
        const int hh = hd >> 6, dd = hd & 63;
#pragma unroll
        for (int rg = 0; rg < 4; ++rg) {
          const int mm = row0 + wr * 64 + mt * 16 + g * 4 + rg;
          const int b = mm >> 11, n = mm & 2047;
          const size_t bh = (size_t)(b * 16 + hh);
          const float v = acc[mt][nt][rg];
          if (which == 0)      q_h[(bh * 2048 + n) * 64 + dd] = (_Float16)(v * qscale);
          else if (which == 1) k_h[(bh * 2048 + n) * 64 + dd] = (_Float16)v;
          else                 v_t[(bh * 64 + dd) * 2048 + n] = (_Float16)v;
        }
      }
    }
  } else {
#pragma unroll
    for (int mt = 0; mt < 4; ++mt) {
#pragma unroll
      for (int nt = 0; nt < 4; ++nt) {
        const int j = col0 + wc * 64 + nt * 16 + r16;
        const float bv = bias[j];
#pragma unroll
        for (int rg = 0; rg < 4; ++rg) {
          const int mm = row0 + wr * 64 + mt * 16 + g * 4 + rg;
          outF[(size_t)mm * Nn + j] = acc[mt][nt][rg] + bv;
        }
      }
    }
  }
}

// ---------------------------------------------------------------- flash attention (v8)
// R6 geometry (4 waves x 64 q = 256 q/block, grid 512) + 3-buffer counted-vmcnt
// pipeline: per tile {vmcnt(4); s_barrier; stage t+2; compute t} -- the barrier
// never drains the in-flight prefetch (T4 mechanism at tile granularity).
__device__ __forceinline__ void stage_kv(const _Float16* Kg, const _Float16* Vg,
                                         _Float16* KsB, _Float16* VsB,
                                         int kv0, int sr, int sc8, int wid) {
#pragma unroll
  for (int i = 0; i < 2; ++i) {
    int r = i * 32 + sr;
    gld16(Kg + (size_t)(kv0 + r) * 64 + (sc8 ^ ((r & 7) * 8)), KsB + i * 2048 + wid * 512);
    gld16(Vg + (size_t)r * 2048 + kv0 + (sc8 ^ ((r & 7) * 8)), VsB + i * 2048 + wid * 512);
  }
}

__global__ __launch_bounds__(256, 2)
void attn_kernel(const _Float16* __restrict__ Qall, const _Float16* __restrict__ Kall,
                 const _Float16* __restrict__ Vtall, _Float16* __restrict__ Oall) {
  __shared__ _Float16 smem[3][2][64 * 64];   // 3 bufs x (K,V) = 48 KB
  const int tid = threadIdx.x;
  const int wid = tid >> 6, lane = tid & 63;
  const int g = lane >> 4, r16 = lane & 15;
  // bijective XCD remap (nwg=512): 8 q-tiles of one (b,h) contiguous on one XCD
  const int blk = (blockIdx.x & 7) * 64 + (blockIdx.x >> 3);
  const int qt = blk & 7;
  const int bh = blk >> 3;
  const _Float16* Qg = Qall + (size_t)bh * (2048 * 64);
  const _Float16* Kg = Kall + (size_t)bh * (2048 * 64);
  const _Float16* Vg = Vtall + (size_t)bh * (2048 * 64);
  const int q0 = qt * 256;
  const int sr = tid >> 3, sc8 = (tid & 7) * 8;

  // Q fragments: 8 global loads (oldest in vmcnt queue)
  h8 qf[4][2];
#pragma unroll
  for (int qb = 0; qb < 4; ++qb) {
    const int qrow = q0 + wid * 64 + qb * 16 + r16;
#pragma unroll
    for (int kd = 0; kd < 2; ++kd)
      qf[qb][kd] = *(const h8*)(Qg + (size_t)qrow * 64 + kd * 32 + g * 8);
  }
  // prefetch tiles 0,1 (4 loads each)
  stage_kv(Kg, Vg, smem[0][0], smem[0][1], 0, sr, sc8, wid);
  stage_kv(Kg, Vg, smem[1][0], smem[1][1], 64, sr, sc8, wid);

  f32x4 ot[4][4] = {};
  float m[4], l[4];
#pragma unroll
  for (int qb = 0; qb < 4; ++qb) { m[qb] = -3.0e38f; l[qb] = 0.f; }

  auto compute = [&](const _Float16* KsB, const _Float16* VsB) {
    h8 kf[4][2];
#pragma unroll
    for (int kb = 0; kb < 4; ++kb) {
      const int krow = kb * 16 + r16;
#pragma unroll
      for (int kd = 0; kd < 2; ++kd)
        kf[kb][kd] = *(const h8*)(KsB + krow * 64 + ((kd * 32 + g * 8) ^ ((krow & 7) * 8)));
    }
    h4 vf[4][4];
#pragma unroll
    for (int db = 0; db < 4; ++db) {
      const int vrow = db * 16 + r16;
#pragma unroll
      for (int kg = 0; kg < 4; ++kg)
        vf[db][kg] = *(const h4*)(VsB + vrow * 64 + ((kg * 16 + g * 4) ^ ((vrow & 7) * 8)));
    }
#pragma unroll
    for (int qb = 0; qb < 4; ++qb) {
      f32x4 st[4];
      __builtin_amdgcn_s_setprio(1);
#pragma unroll
      for (int kb = 0; kb < 4; ++kb) {
        f32x4 z = {};
        st[kb] = __builtin_amdgcn_mfma_f32_16x16x32_f16(kf[kb][0], qf[qb][0], z, 0, 0, 0);
      }
#pragma unroll
      for (int kb = 0; kb < 4; ++kb)
        st[kb] = __builtin_amdgcn_mfma_f32_16x16x32_f16(kf[kb][1], qf[qb][1], st[kb], 0, 0, 0);
      __builtin_amdgcn_s_setprio(0);

      float a0 = fmaxf(fmaxf(st[0][0], st[0][1]), fmaxf(st[0][2], st[0][3]));
      float a1 = fmaxf(fmaxf(st[1][0], st[1][1]), fmaxf(st[1][2], st[1][3]));
      float a2 = fmaxf(fmaxf(st[2][0], st[2][1]), fmaxf(st[2][2], st[2][3]));
      float a3 = fmaxf(fmaxf(st[3][0], st[3][1]), fmaxf(st[3][2], st[3][3]));
      float pmax = fmaxf(fmaxf(a0, a1), fmaxf(a2, a3));
      pmax = fmaxf(pmax, __shfl_xor(pmax, 16));
      pmax = fmaxf(pmax, __shfl_xor(pmax, 32));
      if (__any(pmax > m[qb] + 8.f)) {   // defer-max
        const float mn = fmaxf(m[qb], pmax);
        const float corr = __builtin_amdgcn_exp2f(m[qb] - mn);
        l[qb] *= corr;
#pragma unroll
        for (int db = 0; db < 4; ++db) ot[qb][db] *= corr;
        m[qb] = mn;
      }
      float rs = 0.f;
      h4 pb[4];
#pragma unroll
      for (int kb = 0; kb < 4; ++kb) {
        float p0 = __builtin_amdgcn_exp2f(st[kb][0] - m[qb]);
        float p1 = __builtin_amdgcn_exp2f(st[kb][1] - m[qb]);
        float p2 = __builtin_amdgcn_exp2f(st[kb][2] - m[qb]);
        float p3 = __builtin_amdgcn_exp2f(st[kb][3] - m[qb]);
        rs += (p0 + p1) + (p2 + p3);
        pb[kb] = pack4(p0, p1, p2, p3);
      }
      rs += __shfl_xor(rs, 16);
      rs += __shfl_xor(rs, 32);
      l[qb] += rs;
      __builtin_amdgcn_s_setprio(1);
#pragma unroll
      for (int kg = 0; kg < 4; ++kg)
#pragma unroll
        for (int db = 0; db < 4; ++db)
          ot[qb][db] = __builtin_amdgcn_mfma_f32_16x16x16f16(vf[db][kg], pb[kg], ot[qb][db], 0, 0, 0);
      __builtin_amdgcn_s_setprio(0);
    }
  };

  // one pipeline step: wait current tile's loads (vmcnt(4): next tiles stay in
  // flight), barrier (cross-wave visibility), stage tile t+2, compute tile t.
  auto step = [&](int cb, int sb, int stile, int waitn) {
    if (waitn == 0) asm volatile("s_waitcnt vmcnt(0)" ::: "memory");
    else            asm volatile("s_waitcnt vmcnt(4)" ::: "memory");
    __builtin_amdgcn_s_barrier();
    __builtin_amdgcn_sched_barrier(0);
    if (stile < 32)
      stage_kv(Kg, Vg, smem[sb][0], smem[sb][1], stile * 64, sr, sc8, wid);
    compute(smem[cb][0], smem[cb][1]);
  };

#pragma unroll 1
  for (int tt = 0; tt < 10; ++tt) {
    const int t0 = tt * 3;
    step(0, 2, t0 + 2, 4);
    step(1, 0, t0 + 3, 4);
    step(2, 1, t0 + 4, 4);
  }
  step(0, 0, 32, 4);   // tile 30 (stage nothing; tile 31's loads stay in flight)
  step(1, 0, 32, 0);   // tile 31 (drain)

  __syncthreads();     // all waves done reading KV before epilogue overwrite

  // epilogue: O^T -> smem[0..1] (32 KB, swizzled) -> coalesced 16B stores
  _Float16* olds = &smem[0][0][0];
#pragma unroll
  for (int qb = 0; qb < 4; ++qb) {
    const float inv = 1.f / l[qb];
    const int qrow = wid * 64 + qb * 16 + r16;
    const int x = (qrow & 7) * 8;
#pragma unroll
    for (int db = 0; db < 4; ++db) {
      h4 o;
#pragma unroll
      for (int rg = 0; rg < 4; ++rg) o[rg] = (_Float16)(ot[qb][db][rg] * inv);
      *(h4*)(olds + qrow * 64 + ((db * 16 + g * 4) ^ x)) = o;
    }
  }
  __syncthreads();
  const int bb = bh >> 4, hh = bh & 15;
#pragma unroll
  for (int i = 0; i < 8; ++i) {
    const int idx = tid + i * 256;
    const int q = idx >> 3, c = idx & 7;
    h8 vv = *(const h8*)(olds + q * 64 + ((c * 8) ^ ((q & 7) * 8)));
    *(h8*)(Oall + ((size_t)(bb * 2048 + q0 + q) * 1024 + hh * 64 + c * 8)) = vv;
  }
}

// ---------------------------------------------------------------- launch
extern "C" void kernel_launch(void* const* d_in, const int* in_sizes, int n_in,
                              void* d_out, int out_size, void* d_ws, size_t ws_size,
                              hipStream_t stream) {
  const float* x     = (const float*)d_in[0];
  const float* w_qkv = (const float*)d_in[1];
  const float* w_out = (const float*)d_in[2];
  const float* b_out = (const float*)d_in[3];
  float* out = (float*)d_out;

  char* ws = (char*)d_ws;
  _Float16* x_h    = (_Float16*)(ws);                    // 16 MB
  _Float16* wqkv_t = (_Float16*)(ws + 16777216);         // 6 MB
  _Float16* wout_t = (_Float16*)(ws + 23068672);         // 2 MB
  _Float16* q_h    = (_Float16*)(ws + 25165824);         // 16 MB [b,h,n,d] (pre-scaled)
  _Float16* k_h    = (_Float16*)(ws + 41943040);         // 16 MB [b,h,n,d]
  _Float16* v_t    = (_Float16*)(ws + 58720256);         // 16 MB [b,h,d,n]
  _Float16* o_h    = (_Float16*)(ws + 75497472);         // 16 MB [b,n,h*d]

  hipLaunchKernelGGL(cvt_f32_h, dim3(2048), dim3(256), 0, stream, x, x_h, (8192 * 1024) / 8);
  hipLaunchKernelGGL(transpose_cvt, dim3(96, 32), dim3(256), 0, stream, w_qkv, wqkv_t, 1024, 3072);
  hipLaunchKernelGGL(transpose_cvt, dim3(32, 32), dim3(256), 0, stream, w_out, wout_t, 1024, 1024);

  hipLaunchKernelGGL((gemm_kernel<0>), dim3(64, 24), dim3(256), 0, stream,
                     x_h, wqkv_t, nullptr, nullptr, q_h, k_h, v_t, 3072, 1024);

  hipLaunchKernelGGL(attn_kernel, dim3(512), dim3(256), 0, stream, q_h, k_h, v_t, o_h);

  hipLaunchKernelGGL((gemm_kernel<1>), dim3(64, 8), dim3(256), 0, stream,
                     o_h, wout_t, out, b_out, nullptr, nullptr, nullptr, 1024, 1024);
}